// Round 9
// baseline (171.009 us; speedup 1.0000x reference)
//
#include <hip/hip_runtime.h>

#define T_STEPS 512
#define G_CELLS 4096
#define L_UHN   15
#define GRP     4
#define NGRP    (T_STEPS / GRP)
#define RT_T    32
#define PLANE       ((size_t)T_STEPS * G_CELLS)
#define PLANE_BYTES (PLANE * 4)
#define NZF     1e-5f
#define LOG2E   1.44269504088896340736f
#define LOG2_10 3.32192809488736234787f

__device__ __forceinline__ float fexp2(float x) { return __builtin_amdgcn_exp2f(x); }
__device__ __forceinline__ float flog2(float x) { return __builtin_amdgcn_logf(x); }
__device__ __forceinline__ float fpow(float a, float b) { return fexp2(b * flog2(a)); }
__device__ __forceinline__ float fexp(float x) { return fexp2(x * LOG2E); }
__device__ __forceinline__ float fsigmoid(float v) { return 1.0f / (1.0f + fexp(-v)); }
__device__ __forceinline__ float fdescale(float s, float lo, float hi) { return lo + s * (hi - lo); }

// ===================== Pass A: three independent snow-model scans =====================
// MODEL 0 = hbv, 1 = hmets, 2 = simple. Writes w_i * o_i to its plane.
template<int MODEL>
__device__ __forceinline__ void run_snow(const float* __restrict__ x,
                                         const float* __restrict__ pp,
                                         float* __restrict__ dst, int g)
{
    const float ddf_min  = fdescale(fsigmoid(pp[0]), 0.0f, 20.0f);
    const float ddf_plus = fdescale(fsigmoid(pp[1]), 0.0f, 20.0f);
    const float Kcum     = fdescale(fsigmoid(pp[2]), 0.01f, 0.2f);
    const float Tbm      = fdescale(fsigmoid(pp[8]), -2.0f, 3.0f);
    const float ddfsum   = ddf_min + ddf_plus;
    const float ddfK     = ddf_min * Kcum;

    float w;
    {
        float r0 = pp[24], r1 = pp[25], r2 = pp[26];
        float m = fmaxf(fmaxf(r0, r1), r2);
        float e0 = fexp(r0 - m), e1 = fexp(r1 - m), e2 = fexp(r2 - m);
        float inv = 1.0f / (e0 + e1 + e2);
        w = (MODEL == 0) ? e0 * inv : (MODEL == 1) ? e1 * inv : e2 * inv;
    }

    float Kf = 0.f, Tbf = 0.f, SWI = 0.f, exp_fe = 0.f, fcmin = 0.f, fcsum = 0.f, Ccum = 0.f;
    if (MODEL == 0 || MODEL == 1) {
        Kf  = fdescale(fsigmoid(pp[3]), 0.0f, 5.0f);
        Tbf = fdescale(fsigmoid(pp[5]), -5.0f, 2.0f);
    }
    if (MODEL == 0) SWI = fdescale(fsigmoid(pp[7]), 0.0f, 0.4f);
    if (MODEL == 1) {
        exp_fe = fdescale(fsigmoid(pp[4]),  0.0f, 1.0f);
        Ccum   = fdescale(fsigmoid(pp[6]),  0.005f, 0.05f);
        fcmin  = fdescale(fsigmoid(pp[9]),  0.0f, 0.1f);
        fcsum  = fcmin + fdescale(fsigmoid(pp[10]), 0.01f, 0.25f);
    }

    float sp = 0.f, lw = 0.f, cm = 0.f;

    float bufA[GRP][2], bufB[GRP][2], bufC[GRP][2];
    #pragma unroll
    for (int j = 0; j < GRP; ++j) {
        size_t a = ((size_t)j * G_CELLS + (size_t)g) * 3;
        bufA[j][0] = x[a]; bufA[j][1] = x[a + 1];
    }
    #pragma unroll
    for (int j = 0; j < GRP; ++j) {
        size_t a = ((size_t)(GRP + j) * G_CELLS + (size_t)g) * 3;
        bufB[j][0] = x[a]; bufB[j][1] = x[a + 1];
    }

    for (int tb = 0; tb < NGRP; ++tb) {
        int tn = tb + 2; if (tn >= NGRP) tn = NGRP - 1;
        #pragma unroll
        for (int j = 0; j < GRP; ++j) {
            size_t a = ((size_t)(tn * GRP + j) * G_CELLS + (size_t)g) * 3;
            bufC[j][0] = x[a]; bufC[j][1] = x[a + 1];
        }

        #pragma unroll
        for (int j = 0; j < GRP; ++j) {
            const int t = tb * GRP + j;
            const float prcp = bufA[j][0], tm = bufA[j][1];
            const float rain = (tm > 0.0f) ? prcp : 0.0f;
            const float snow = prcp - rain;
            float ddf = fminf(ddfsum, fmaf(ddfK, cm, ddf_min));
            float pm  = fmaxf(ddf * (tm - Tbm), 0.0f);
            float o;
            if (MODEL == 0) {
                const float frz = fmaxf(Tbf - tm, NZF);
                float rfz  = fminf(Kf * frz, lw);
                sp = sp + snow + rfz;
                float melt = fminf(pm, sp + snow + rfz);   // reference quirk: sp already updated
                cm = (sp > NZF) ? (cm + melt) : 0.0f;
                sp = fmaxf(sp - melt, NZF);
                float wret = SWI * sp;
                float wtmp = lw + melt + rain;
                o  = fmaxf(wtmp - wret, 0.0f);
                lw = fminf(wtmp, wret);
            } else if (MODEL == 1) {
                const float frz = fmaxf(Tbf - tm, NZF);
                float pfz  = Kf * fpow(frz, exp_fe);
                float rfz  = fminf(pfz, lw);
                lw -= rfz; sp += rfz;
                float melt = fminf(pm, sp + snow);
                sp = sp + snow - melt;
                cm = (sp > NZF) ? (cm + melt) : 0.0f;
                float wrf  = fmaxf(fcsum * (1.0f - Ccum * cm), fcmin);
                float wret = wrf * sp;
                float wtmp = lw + melt + rain;
                o  = fmaxf(wtmp - wret, 0.0f);
                lw = fminf(wtmp, wret);
                cm = (sp > NZF) ? (cm + melt) : 0.0f;      // reference quirk: cm updated twice
            } else {
                float melt = fminf(pm, sp);
                sp = sp + snow - melt;
                o  = melt + rain;
                cm = (sp > NZF) ? (cm + melt) : 0.0f;
            }
            dst[(size_t)t * G_CELLS + (size_t)g] = w * o;
        }

        #pragma unroll
        for (int j = 0; j < GRP; ++j) {
            bufA[j][0] = bufB[j][0]; bufA[j][1] = bufB[j][1];
            bufB[j][0] = bufC[j][0]; bufB[j][1] = bufC[j][1];
        }
    }
}

__global__ __launch_bounds__(256, 1) void snow_kernel(
    const float* __restrict__ x, const float* __restrict__ params, float* __restrict__ oo)
{
    const int g = blockIdx.x * 256 + threadIdx.x;
    const float* pp = params + ((size_t)(T_STEPS - 1) * G_CELLS + (size_t)g) * 39;
    float* dst = oo + (size_t)blockIdx.y * PLANE;
    if      (blockIdx.y == 0) run_snow<0>(x, pp, dst, g);
    else if (blockIdx.y == 1) run_snow<1>(x, pp, dst, g);
    else                      run_snow<2>(x, pp, dst, g);
}

// ===================== Pass B: vadose/phreatic scan =====================
__global__ __launch_bounds__(256, 1) void vadose_kernel(
    const float* __restrict__ x, const float* __restrict__ params,
    const float* __restrict__ oo, float* __restrict__ quick, float* __restrict__ base)
{
    const int g = blockIdx.x * 256 + threadIdx.x;
    const float* pp = params + ((size_t)(T_STEPS - 1) * G_CELLS + (size_t)g) * 39;

    const float vmax        = fdescale(fsigmoid(pp[11]), 0.001f, 500.0f);
    const float hmets_alpha = fdescale(fsigmoid(pp[12]), 0.0f, 1.0f);
    const float vic_beta    = fdescale(fsigmoid(pp[13]), 0.1f, 3.0f);
    const float hbv_beta    = fdescale(fsigmoid(pp[14]), 0.5f, 3.0f);
    const float quickflow_k = fdescale(fsigmoid(pp[15]), -5.0f, -2.0f);
    const float qn          = fdescale(fsigmoid(pp[16]), 0.5f, 2.0f);
    const float mmax        = fdescale(fsigmoid(pp[17]), 0.0f, 100.0f);
    const float lamb        = fdescale(fsigmoid(pp[18]), 5.0f, 10.0f);
    const float baseflow_k  = fdescale(fsigmoid(pp[19]), -5.0f, -1.0f);
    const float bn          = fdescale(fsigmoid(pp[20]), 0.5f, 2.0f);
    const float ET_eff      = fdescale(fsigmoid(pp[21]), 0.0f, 3.0f);
    const float cv2p        = fdescale(fsigmoid(pp[22]), 1e-5f, 0.02f);

    float w4, w5, w6, w7, w8, w9, w10, w11;
    {
        float r0 = pp[27], r1 = pp[28], r2 = pp[29];
        float m = fmaxf(fmaxf(r0, r1), r2);
        float e0 = fexp(r0 - m), e1 = fexp(r1 - m), e2 = fexp(r2 - m);
        float inv = 1.0f / (e0 + e1 + e2);
        w4 = e0 * inv; w5 = e1 * inv; w6 = e2 * inv;
    }
    {
        float r0 = pp[30], r1 = pp[31], r2 = pp[32];
        float m = fmaxf(fmaxf(r0, r1), r2);
        float e0 = fexp(r0 - m), e1 = fexp(r1 - m), e2 = fexp(r2 - m);
        float inv = 1.0f / (e0 + e1 + e2);
        w7 = e0 * inv; w8 = e1 * inv; w9 = e2 * inv;
    }
    {
        float r0 = pp[33], r1 = pp[34];
        float m = fmaxf(r0, r1);
        float e0 = fexp(r0 - m), e1 = fexp(r1 - m);
        float inv = 1.0f / (e0 + e1);
        w10 = e0 * inv; w11 = e1 * inv;
    }

    const float inv_vmax    = 1.0f / vmax;
    const float qk10        = fexp2(quickflow_k * LOG2_10);
    const float bk10        = fexp2(baseflow_k * LOG2_10);
    const float qf_top_coef = mmax * (vmax / qn) * fexp2(-qn * flog2(lamb));
    const float c_b1 = w10 * bk10, c_b2 = w11 * bk10, w7qk = w7 * qk10;

    const float* oo1 = oo;
    const float* oo2 = oo + PLANE;
    const float* oo3 = oo + 2 * PLANE;

    float vad = 0.f, phr = 0.f;

    // triple-buffered inputs: {oo1, oo2, oo3, pet}
    float bufA[GRP][4], bufB[GRP][4], bufC[GRP][4];
    #pragma unroll
    for (int j = 0; j < GRP; ++j) {
        size_t a = (size_t)j * G_CELLS + (size_t)g;
        bufA[j][0] = oo1[a]; bufA[j][1] = oo2[a]; bufA[j][2] = oo3[a]; bufA[j][3] = x[a * 3 + 2];
    }
    #pragma unroll
    for (int j = 0; j < GRP; ++j) {
        size_t a = (size_t)(GRP + j) * G_CELLS + (size_t)g;
        bufB[j][0] = oo1[a]; bufB[j][1] = oo2[a]; bufB[j][2] = oo3[a]; bufB[j][3] = x[a * 3 + 2];
    }

    for (int tb = 0; tb < NGRP; ++tb) {
        int tn = tb + 2; if (tn >= NGRP) tn = NGRP - 1;
        #pragma unroll
        for (int j = 0; j < GRP; ++j) {
            size_t a = (size_t)(tn * GRP + j) * G_CELLS + (size_t)g;
            bufC[j][0] = oo1[a]; bufC[j][1] = oo2[a]; bufC[j][2] = oo3[a]; bufC[j][3] = x[a * 3 + 2];
        }

        #pragma unroll
        for (int j = 0; j < GRP; ++j) {
            const int t = tb * GRP + j;
            const float rr  = bufA[j][0] + bufA[j][1] + bufA[j][2];
            const float pet = bufA[j][3];

            float vv = vad * inv_vmax;
            float sprop = fminf(fmaxf(vv, NZF), 1.0f - NZF);
            float l1 = flog2(1.0f - sprop);
            float phbv = fexp2(hbv_beta * l1);
            float pvic = fexp2(vic_beta * l1);
            float inf = w4 * rr * phbv + w5 * rr * (1.0f - hmets_alpha * vv) + w6 * rr * (1.0f - pvic);
            inf = fminf(fmaxf(inf, 0.0f), rr);
            float surface = rr - inf;
            vad += inf;
            vv = vad * inv_vmax;
            sprop = fminf(fmaxf(vv, NZF), 1.0f - NZF);
            float et = fminf(pet * ET_eff * sprop, vad);
            vad -= et;
            float spq    = fexp2(qn * flog2(sprop));
            float qf_top = fminf(qf_top_coef * spq, vad);
            float qf_vic = fminf(mmax * spq, vad);
            float qf = fminf(w7qk * vad + w8 * qf_top + w9 * qf_vic, vad);
            vad -= qf;
            float perc = cv2p * vad;
            vad -= perc;
            phr += perc;
            float pb = fexp2(bn * flog2(fmaxf(phr, NZF)));
            float bf = fminf(c_b1 * phr + c_b2 * pb, phr);
            phr -= bf;

            const size_t row = (size_t)t * G_CELLS + (size_t)g;
            quick[row] = surface + qf;
            base[row]  = bf;
        }

        #pragma unroll
        for (int j = 0; j < GRP; ++j) {
            bufA[j][0] = bufB[j][0]; bufA[j][1] = bufB[j][1]; bufA[j][2] = bufB[j][2]; bufA[j][3] = bufB[j][3];
            bufB[j][0] = bufC[j][0]; bufB[j][1] = bufC[j][1]; bufB[j][2] = bufC[j][2]; bufB[j][3] = bufC[j][3];
        }
    }
}

// ===================== Pass C: tiled routing (proven in R7/R8) =====================
__device__ __forceinline__ void make_uh(float a1, float b1, float a2, float b2,
                                        float* uh1, float* uh2) {
    const float LOG2T[L_UHN] = {
        -1.0f, 0.58496250072116f, 1.32192809488736f, 1.80735492205760f,
        2.16992500144231f, 2.45943161863730f, 2.70043971814109f,
        2.90689059560852f, 3.08746284125034f, 3.24792751344359f,
        3.39231742277876f, 3.52356195605701f, 3.64385618977472f,
        3.75488750216347f, 3.85798099512757f };
    float rb1 = LOG2E / b1, rb2 = LOG2E / b2;
    float s1 = 0.0f, s2 = 0.0f;
    #pragma unroll
    for (int k = 0; k < L_UHN; ++k) {
        float tk = (float)k + 0.5f;
        float v1 = fexp2((a1 - 1.0f) * LOG2T[k] - tk * rb1);
        float v2 = fexp2((a2 - 1.0f) * LOG2T[k] - tk * rb2);
        uh1[k] = v1; uh2[k] = v2; s1 += v1; s2 += v2;
    }
    float i1 = 1.0f / s1, i2 = 1.0f / s2;
    #pragma unroll
    for (int k = 0; k < L_UHN; ++k) { uh1[k] *= i1; uh2[k] *= i2; }
}

__global__ __launch_bounds__(64, 1) void route_tiled_kernel(
    const float* __restrict__ quick,
    const float* __restrict__ base,
    const float* __restrict__ params,
    float* __restrict__ out)
{
    const int g  = blockIdx.x * 64 + threadIdx.x;
    const int t0 = blockIdx.y * RT_T;

    const float* pp = params + ((size_t)(T_STEPS - 1) * G_CELLS + (size_t)g) * 39;
    float a1 = fdescale(fsigmoid(pp[35]), 0.3f, 20.0f);
    float b1 = fdescale(fsigmoid(pp[36]), 0.01f, 5.0f);
    float a2 = fdescale(fsigmoid(pp[37]), 0.5f, 13.0f);
    float b2 = fdescale(fsigmoid(pp[38]), 0.15f, 1.5f);
    float uh1[L_UHN], uh2[L_UHN];
    make_uh(a1, b1, a2, b2, uh1, uh2);

    float qw[RT_T + L_UHN - 1], bw[RT_T + L_UHN - 1];
    #pragma unroll
    for (int i = 0; i < RT_T + L_UHN - 1; ++i) {
        int t = t0 + i - (L_UHN - 1);
        bool ok = (t >= 0);
        size_t a = (size_t)(ok ? t : 0) * G_CELLS + (size_t)g;
        qw[i] = ok ? quick[a] : 0.0f;
        bw[i] = ok ? base[a]  : 0.0f;
    }

    #pragma unroll
    for (int j = 0; j < RT_T; ++j) {
        float acc = 0.0f;
        #pragma unroll
        for (int k = 0; k < L_UHN; ++k)
            acc = fmaf(uh1[k], qw[j + L_UHN - 1 - k], fmaf(uh2[k], bw[j + L_UHN - 1 - k], acc));
        out[(size_t)(t0 + j) * G_CELLS + (size_t)g] = acc;
    }
}

// ===================== fused fallback (R4 structure, verified) =====================
__device__ __forceinline__ void fused_cell(const float* __restrict__ x,
                                           const float* __restrict__ pp,
                                           float* __restrict__ out, int g)
{
    const float ddf_min     = fdescale(fsigmoid(pp[0]),  0.0f, 20.0f);
    const float ddf_plus    = fdescale(fsigmoid(pp[1]),  0.0f, 20.0f);
    const float Kcum        = fdescale(fsigmoid(pp[2]),  0.01f, 0.2f);
    const float Kf          = fdescale(fsigmoid(pp[3]),  0.0f, 5.0f);
    const float exp_fe      = fdescale(fsigmoid(pp[4]),  0.0f, 1.0f);
    const float Tbf         = fdescale(fsigmoid(pp[5]), -5.0f, 2.0f);
    const float Ccum        = fdescale(fsigmoid(pp[6]),  0.005f, 0.05f);
    const float SWI         = fdescale(fsigmoid(pp[7]),  0.0f, 0.4f);
    const float Tbm         = fdescale(fsigmoid(pp[8]), -2.0f, 3.0f);
    const float fcmin       = fdescale(fsigmoid(pp[9]),  0.0f, 0.1f);
    const float fcmin_plus  = fdescale(fsigmoid(pp[10]), 0.01f, 0.25f);
    const float vmax        = fdescale(fsigmoid(pp[11]), 0.001f, 500.0f);
    const float hmets_alpha = fdescale(fsigmoid(pp[12]), 0.0f, 1.0f);
    const float vic_beta    = fdescale(fsigmoid(pp[13]), 0.1f, 3.0f);
    const float hbv_beta    = fdescale(fsigmoid(pp[14]), 0.5f, 3.0f);
    const float quickflow_k = fdescale(fsigmoid(pp[15]), -5.0f, -2.0f);
    const float qn          = fdescale(fsigmoid(pp[16]), 0.5f, 2.0f);
    const float mmax        = fdescale(fsigmoid(pp[17]), 0.0f, 100.0f);
    const float lamb        = fdescale(fsigmoid(pp[18]), 5.0f, 10.0f);
    const float baseflow_k  = fdescale(fsigmoid(pp[19]), -5.0f, -1.0f);
    const float bn          = fdescale(fsigmoid(pp[20]), 0.5f, 2.0f);
    const float ET_eff      = fdescale(fsigmoid(pp[21]), 0.0f, 3.0f);
    const float cv2p        = fdescale(fsigmoid(pp[22]), 1e-5f, 0.02f);

    float w1,w2,w3,w4,w5,w6,w7,w8,w9,w10,w11;
    {
        float m = fmaxf(fmaxf(pp[24], pp[25]), pp[26]);
        float e0 = fexp(pp[24]-m), e1 = fexp(pp[25]-m), e2 = fexp(pp[26]-m);
        float inv = 1.0f/(e0+e1+e2); w1=e0*inv; w2=e1*inv; w3=e2*inv;
    }
    {
        float m = fmaxf(fmaxf(pp[27], pp[28]), pp[29]);
        float e0 = fexp(pp[27]-m), e1 = fexp(pp[28]-m), e2 = fexp(pp[29]-m);
        float inv = 1.0f/(e0+e1+e2); w4=e0*inv; w5=e1*inv; w6=e2*inv;
    }
    {
        float m = fmaxf(fmaxf(pp[30], pp[31]), pp[32]);
        float e0 = fexp(pp[30]-m), e1 = fexp(pp[31]-m), e2 = fexp(pp[32]-m);
        float inv = 1.0f/(e0+e1+e2); w7=e0*inv; w8=e1*inv; w9=e2*inv;
    }
    {
        float m = fmaxf(pp[33], pp[34]);
        float e0 = fexp(pp[33]-m), e1 = fexp(pp[34]-m);
        float inv = 1.0f/(e0+e1); w10=e0*inv; w11=e1*inv;
    }

    float uh1[L_UHN], uh2[L_UHN];
    make_uh(fdescale(fsigmoid(pp[35]), 0.3f, 20.0f), fdescale(fsigmoid(pp[36]), 0.01f, 5.0f),
            fdescale(fsigmoid(pp[37]), 0.5f, 13.0f), fdescale(fsigmoid(pp[38]), 0.15f, 1.5f),
            uh1, uh2);

    const float ddfsum = ddf_min + ddf_plus;
    const float ddfK   = ddf_min * Kcum;
    const float inv_vmax = 1.0f / vmax;
    const float qk10 = fexp2(quickflow_k * LOG2_10);
    const float bk10 = fexp2(baseflow_k * LOG2_10);
    const float qf_top_coef = mmax * (vmax / qn) * fexp2(-qn * flog2(lamb));
    const float fcsum = fcmin + fcmin_plus;
    const float c_b1 = w10 * bk10, c_b2 = w11 * bk10, w7qk = w7 * qk10;

    float sp1=0,lw1=0,cm1=0, sp2=0,lw2=0,cm2=0, sp3=0,cm3=0, vad=0, phr=0;
    float fut[L_UHN];
    #pragma unroll
    for (int k = 0; k < L_UHN; ++k) fut[k] = 0.0f;

    for (int t = 0; t < T_STEPS; ++t) {
        size_t a = ((size_t)t * G_CELLS + (size_t)g) * 3;
        const float prcp = x[a], tm = x[a+1], pet = x[a+2];
        const float rain = (tm > 0.0f) ? prcp : 0.0f;
        const float snow = prcp - rain;
        const float frz = fmaxf(Tbf - tm, NZF);

        float o1;
        {
            float ddf = fminf(ddfsum, fmaf(ddfK, cm1, ddf_min));
            float pm  = fmaxf(ddf * (tm - Tbm), 0.0f);
            float rfz = fminf(Kf * frz, lw1);
            sp1 = sp1 + snow + rfz;
            float melt = fminf(pm, sp1 + snow + rfz);
            cm1 = (sp1 > NZF) ? (cm1 + melt) : 0.0f;
            sp1 = fmaxf(sp1 - melt, NZF);
            float wret = SWI * sp1, wtmp = lw1 + melt + rain;
            o1 = fmaxf(wtmp - wret, 0.0f);
            lw1 = fminf(wtmp, wret);
        }
        float o2;
        {
            float ddf = fminf(ddfsum, fmaf(ddfK, cm2, ddf_min));
            float pm  = fmaxf(ddf * (tm - Tbm), 0.0f);
            float pfz = Kf * fpow(frz, exp_fe);
            float rfz = fminf(pfz, lw2);
            lw2 -= rfz; sp2 += rfz;
            float melt = fminf(pm, sp2 + snow);
            sp2 = sp2 + snow - melt;
            cm2 = (sp2 > NZF) ? (cm2 + melt) : 0.0f;
            float wrf = fmaxf(fcsum * (1.0f - Ccum * cm2), fcmin);
            float wret = wrf * sp2, wtmp = lw2 + melt + rain;
            o2 = fmaxf(wtmp - wret, 0.0f);
            lw2 = fminf(wtmp, wret);
            cm2 = (sp2 > NZF) ? (cm2 + melt) : 0.0f;
        }
        float o3;
        {
            float ddf = fminf(ddfsum, fmaf(ddfK, cm3, ddf_min));
            float pm  = fmaxf(ddf * (tm - Tbm), 0.0f);
            float melt = fminf(pm, sp3);
            sp3 = sp3 + snow - melt;
            o3 = melt + rain;
            cm3 = (sp3 > NZF) ? (cm3 + melt) : 0.0f;
        }

        float rr = w1*o1 + w2*o2 + w3*o3;
        float vv = vad * inv_vmax;
        float sprop = fminf(fmaxf(vv, NZF), 1.0f - NZF);
        float l1 = flog2(1.0f - sprop);
        float phbv = fexp2(hbv_beta * l1);
        float pvic = fexp2(vic_beta * l1);
        float inf = w4*rr*phbv + w5*rr*(1.0f - hmets_alpha*vv) + w6*rr*(1.0f - pvic);
        inf = fminf(fmaxf(inf, 0.0f), rr);
        float surface = rr - inf;
        vad += inf;
        vv = vad * inv_vmax;
        sprop = fminf(fmaxf(vv, NZF), 1.0f - NZF);
        float et = fminf(pet * ET_eff * sprop, vad);
        vad -= et;
        float spq = fexp2(qn * flog2(sprop));
        float qf_top = fminf(qf_top_coef * spq, vad);
        float qf_vic = fminf(mmax * spq, vad);
        float qf = fminf(w7qk*vad + w8*qf_top + w9*qf_vic, vad);
        vad -= qf;
        float perc = cv2p * vad;
        vad -= perc;
        phr += perc;
        float pb = fexp2(bn * flog2(fmaxf(phr, NZF)));
        float bf = fminf(c_b1*phr + c_b2*pb, phr);
        phr -= bf;

        float qt = surface + qf;
        #pragma unroll
        for (int k = 0; k < L_UHN; ++k)
            fut[k] = fmaf(uh1[k], qt, fmaf(uh2[k], bf, fut[k]));
        out[(size_t)t * G_CELLS + (size_t)g] = fut[0];
        #pragma unroll
        for (int k = 0; k < L_UHN - 1; ++k) fut[k] = fut[k + 1];
        fut[L_UHN - 1] = 0.0f;
    }
}

__global__ __launch_bounds__(256) void fused_kernel(
    const float* __restrict__ x, const float* __restrict__ params, float* __restrict__ out)
{
    const int g = blockIdx.x * blockDim.x + threadIdx.x;
    const float* pp = params + ((size_t)(T_STEPS - 1) * G_CELLS + (size_t)g) * 39;
    fused_cell(x, pp, out, g);
}

extern "C" void kernel_launch(void* const* d_in, const int* in_sizes, int n_in,
                              void* d_out, int out_size, void* d_ws, size_t ws_size,
                              hipStream_t stream) {
    const float* x      = (const float*)d_in[0];
    const float* params = (const float*)d_in[1];
    float* out          = (float*)d_out;

    if (ws_size >= 5 * PLANE_BYTES) {
        float* oo    = (float*)d_ws;                 // 3 planes: w1*o1, w2*o2, w3*o3
        float* quick = oo + 3 * PLANE;
        float* base  = quick + PLANE;
        snow_kernel<<<dim3(G_CELLS / 256, 3), dim3(256), 0, stream>>>(x, params, oo);
        vadose_kernel<<<dim3(G_CELLS / 256), dim3(256), 0, stream>>>(x, params, oo, quick, base);
        route_tiled_kernel<<<dim3(G_CELLS / 64, T_STEPS / RT_T), dim3(64), 0, stream>>>(
            quick, base, params, out);
    } else {
        fused_kernel<<<dim3(G_CELLS / 256), dim3(256), 0, stream>>>(x, params, out);
    }
}

// Round 10
// 96.380 us; speedup vs baseline: 1.7743x; 1.7743x over previous
//
#include <hip/hip_runtime.h>

#define T_STEPS 512
#define G_CELLS 4096
#define L_UHN   15
#define GRP     8
#define NGRP    (T_STEPS / GRP)   // 64
#define CPB     64                // cells per block (one lane each)
#define RT_T    32
#define PLANE       ((size_t)T_STEPS * G_CELLS)
#define PLANE_BYTES (PLANE * 4)
#define NZF     1e-5f
#define LOG2E   1.44269504088896340736f
#define LOG2_10 3.32192809488736234787f

__device__ __forceinline__ float fexp2(float x) { return __builtin_amdgcn_exp2f(x); }
__device__ __forceinline__ float flog2(float x) { return __builtin_amdgcn_logf(x); }
__device__ __forceinline__ float fpow(float a, float b) { return fexp2(b * flog2(a)); }
__device__ __forceinline__ float fexp(float x) { return fexp2(x * LOG2E); }
__device__ __forceinline__ float fsigmoid(float v) { return 1.0f / (1.0f + fexp(-v)); }
__device__ __forceinline__ float fdescale(float s, float lo, float hi) { return lo + s * (hi - lo); }

__device__ __forceinline__ void block_barrier() {
    asm volatile("s_waitcnt lgkmcnt(0)" ::: "memory");
    __builtin_amdgcn_s_barrier();
}

// ===================== producer: one snow model per wave =====================
// MODEL 0 = hbv, 1 = hmets, 2 = simple. Writes w_m * o_m into LDS ring.
template<int MODEL>
__device__ __forceinline__ void snow_wave(const float* __restrict__ x,
                                          const float* __restrict__ pp,
                                          float (*ob)[3][GRP][CPB],
                                          int lane, int g)
{
    const float ddf_min  = fdescale(fsigmoid(pp[0]), 0.0f, 20.0f);
    const float ddf_plus = fdescale(fsigmoid(pp[1]), 0.0f, 20.0f);
    const float Kcum     = fdescale(fsigmoid(pp[2]), 0.01f, 0.2f);
    const float Tbm      = fdescale(fsigmoid(pp[8]), -2.0f, 3.0f);
    const float ddfsum   = ddf_min + ddf_plus;
    const float ddfK     = ddf_min * Kcum;

    float w;
    {
        float r0 = pp[24], r1 = pp[25], r2 = pp[26];
        float m = fmaxf(fmaxf(r0, r1), r2);
        float e0 = fexp(r0 - m), e1 = fexp(r1 - m), e2 = fexp(r2 - m);
        float inv = 1.0f / (e0 + e1 + e2);
        w = (MODEL == 0) ? e0 * inv : (MODEL == 1) ? e1 * inv : e2 * inv;
    }

    float Kf = 0.f, Tbf = 0.f, SWI = 0.f, exp_fe = 0.f, fcmin = 0.f, fcsum = 0.f, Ccum = 0.f;
    if (MODEL == 0 || MODEL == 1) {
        Kf  = fdescale(fsigmoid(pp[3]), 0.0f, 5.0f);
        Tbf = fdescale(fsigmoid(pp[5]), -5.0f, 2.0f);
    }
    if (MODEL == 0) SWI = fdescale(fsigmoid(pp[7]), 0.0f, 0.4f);
    if (MODEL == 1) {
        exp_fe = fdescale(fsigmoid(pp[4]),  0.0f, 1.0f);
        Ccum   = fdescale(fsigmoid(pp[6]),  0.005f, 0.05f);
        fcmin  = fdescale(fsigmoid(pp[9]),  0.0f, 0.1f);
        fcsum  = fcmin + fdescale(fsigmoid(pp[10]), 0.01f, 0.25f);
    }

    float sp = 0.f, lw = 0.f, cm = 0.f;

    // processed current-group buffers (input-only precompute: rain, snow, dtm, aux)
    float bR[GRP], bS[GRP], bD[GRP], bX[GRP];
    float rawP[GRP], rawT[GRP];

    #pragma unroll
    for (int j = 0; j < GRP; ++j) {
        size_t a = ((size_t)j * G_CELLS + (size_t)g) * 3;
        rawP[j] = x[a]; rawT[j] = x[a + 1];
    }
    #pragma unroll
    for (int j = 0; j < GRP; ++j) {
        float tm = rawT[j], prcp = rawP[j];
        bR[j] = (tm > 0.0f) ? prcp : 0.0f;
        bS[j] = prcp - bR[j];
        bD[j] = tm - Tbm;
        if (MODEL == 0)      bX[j] = Kf * fmaxf(Tbf - tm, NZF);
        else if (MODEL == 1) bX[j] = Kf * fpow(fmaxf(Tbf - tm, NZF), exp_fe);
        else                 bX[j] = 0.0f;
    }

    for (int k = 0; k <= NGRP; ++k) {
        block_barrier();
        if (k < NGRP) {
            // issue raw loads for next group (waited at the transform below, after compute)
            const int kn = (k + 1 < NGRP) ? k + 1 : NGRP - 1;
            #pragma unroll
            for (int j = 0; j < GRP; ++j) {
                size_t a = ((size_t)(kn * GRP + j) * G_CELLS + (size_t)g) * 3;
                rawP[j] = x[a]; rawT[j] = x[a + 1];
            }

            // compute group k (pure-ALU serial chain; transcendentals hoisted to prefetch)
            const int b = k & 1;
            #pragma unroll
            for (int j = 0; j < GRP; ++j) {
                const float rain = bR[j], snow = bS[j], dtm = bD[j], aux = bX[j];
                float ddf = fminf(ddfsum, fmaf(ddfK, cm, ddf_min));
                float pm  = fmaxf(ddf * dtm, 0.0f);
                float o;
                if (MODEL == 0) {
                    float rfz  = fminf(aux, lw);
                    sp = sp + snow + rfz;
                    float melt = fminf(pm, sp + snow + rfz);   // reference quirk: sp already updated
                    cm = (sp > NZF) ? (cm + melt) : 0.0f;
                    sp = fmaxf(sp - melt, NZF);
                    float wret = SWI * sp;
                    float wtmp = lw + melt + rain;
                    o  = fmaxf(wtmp - wret, 0.0f);
                    lw = fminf(wtmp, wret);
                } else if (MODEL == 1) {
                    float rfz  = fminf(aux, lw);
                    lw -= rfz; sp += rfz;
                    float melt = fminf(pm, sp + snow);
                    sp = sp + snow - melt;
                    cm = (sp > NZF) ? (cm + melt) : 0.0f;
                    float wrf  = fmaxf(fcsum * (1.0f - Ccum * cm), fcmin);
                    float wret = wrf * sp;
                    float wtmp = lw + melt + rain;
                    o  = fmaxf(wtmp - wret, 0.0f);
                    lw = fminf(wtmp, wret);
                    cm = (sp > NZF) ? (cm + melt) : 0.0f;      // reference quirk: cm updated twice
                } else {
                    float melt = fminf(pm, sp);
                    sp = sp + snow - melt;
                    o  = melt + rain;
                    cm = (sp > NZF) ? (cm + melt) : 0.0f;
                }
                ob[b][MODEL][j][lane] = w * o;
            }

            // transform raw -> processed for next group (off the serial chain)
            #pragma unroll
            for (int j = 0; j < GRP; ++j) {
                float tm = rawT[j], prcp = rawP[j];
                bR[j] = (tm > 0.0f) ? prcp : 0.0f;
                bS[j] = prcp - bR[j];
                bD[j] = tm - Tbm;
                if (MODEL == 0)      bX[j] = Kf * fmaxf(Tbf - tm, NZF);
                else if (MODEL == 1) bX[j] = Kf * fpow(fmaxf(Tbf - tm, NZF), exp_fe);
                else                 bX[j] = 0.0f;
            }
        }
    }
}

// ===================== consumer: vadose/phreatic chain, one group behind =====================
__device__ __forceinline__ void vadose_wave(const float* __restrict__ x,
                                            const float* __restrict__ pp,
                                            float (*ob)[3][GRP][CPB],
                                            float* __restrict__ quick,
                                            float* __restrict__ base,
                                            int lane, int g)
{
    const float vmax        = fdescale(fsigmoid(pp[11]), 0.001f, 500.0f);
    const float hmets_alpha = fdescale(fsigmoid(pp[12]), 0.0f, 1.0f);
    const float vic_beta    = fdescale(fsigmoid(pp[13]), 0.1f, 3.0f);
    const float hbv_beta    = fdescale(fsigmoid(pp[14]), 0.5f, 3.0f);
    const float quickflow_k = fdescale(fsigmoid(pp[15]), -5.0f, -2.0f);
    const float qn          = fdescale(fsigmoid(pp[16]), 0.5f, 2.0f);
    const float mmax        = fdescale(fsigmoid(pp[17]), 0.0f, 100.0f);
    const float lamb        = fdescale(fsigmoid(pp[18]), 5.0f, 10.0f);
    const float baseflow_k  = fdescale(fsigmoid(pp[19]), -5.0f, -1.0f);
    const float bn          = fdescale(fsigmoid(pp[20]), 0.5f, 2.0f);
    const float ET_eff      = fdescale(fsigmoid(pp[21]), 0.0f, 3.0f);
    const float cv2p        = fdescale(fsigmoid(pp[22]), 1e-5f, 0.02f);

    float w4, w5, w6, w7, w8, w9, w10, w11;
    {
        float r0 = pp[27], r1 = pp[28], r2 = pp[29];
        float m = fmaxf(fmaxf(r0, r1), r2);
        float e0 = fexp(r0 - m), e1 = fexp(r1 - m), e2 = fexp(r2 - m);
        float inv = 1.0f / (e0 + e1 + e2);
        w4 = e0 * inv; w5 = e1 * inv; w6 = e2 * inv;
    }
    {
        float r0 = pp[30], r1 = pp[31], r2 = pp[32];
        float m = fmaxf(fmaxf(r0, r1), r2);
        float e0 = fexp(r0 - m), e1 = fexp(r1 - m), e2 = fexp(r2 - m);
        float inv = 1.0f / (e0 + e1 + e2);
        w7 = e0 * inv; w8 = e1 * inv; w9 = e2 * inv;
    }
    {
        float r0 = pp[33], r1 = pp[34];
        float m = fmaxf(r0, r1);
        float e0 = fexp(r0 - m), e1 = fexp(r1 - m);
        float inv = 1.0f / (e0 + e1);
        w10 = e0 * inv; w11 = e1 * inv;
    }

    const float inv_vmax    = 1.0f / vmax;
    const float qk10        = fexp2(quickflow_k * LOG2_10);
    const float bk10        = fexp2(baseflow_k * LOG2_10);
    const float qf_top_coef = mmax * (vmax / qn) * fexp2(-qn * flog2(lamb));
    const float c_b1 = w10 * bk10, c_b2 = w11 * bk10, w7qk = w7 * qk10;

    float vad = 0.f, phr = 0.f;

    float pe[GRP], rawPet[GRP];
    #pragma unroll
    for (int j = 0; j < GRP; ++j)
        rawPet[j] = x[((size_t)j * G_CELLS + (size_t)g) * 3 + 2];
    #pragma unroll
    for (int j = 0; j < GRP; ++j) pe[j] = rawPet[j] * ET_eff;

    for (int k = 0; k <= NGRP; ++k) {
        block_barrier();
        if (k > 0) {
            const int kg = k - 1;
            // issue pet loads for group k (used next iteration)
            const int kn = (k < NGRP) ? k : NGRP - 1;
            #pragma unroll
            for (int j = 0; j < GRP; ++j)
                rawPet[j] = x[((size_t)(kn * GRP + j) * G_CELLS + (size_t)g) * 3 + 2];

            // gather rr for group kg from LDS ring
            const int b = kg & 1;
            float rr[GRP];
            #pragma unroll
            for (int j = 0; j < GRP; ++j)
                rr[j] = (ob[b][0][j][lane] + ob[b][1][j][lane]) + ob[b][2][j][lane];

            #pragma unroll
            for (int j = 0; j < GRP; ++j) {
                const float rrj = rr[j];
                float vv = vad * inv_vmax;
                float sprop = fminf(fmaxf(vv, NZF), 1.0f - NZF);
                float l1 = flog2(1.0f - sprop);
                float phbv = fexp2(hbv_beta * l1);
                float pvic = fexp2(vic_beta * l1);
                float inf = w4 * rrj * phbv + w5 * rrj * (1.0f - hmets_alpha * vv)
                          + w6 * rrj * (1.0f - pvic);
                inf = fminf(fmaxf(inf, 0.0f), rrj);
                float surface = rrj - inf;
                vad += inf;
                vv = vad * inv_vmax;
                sprop = fminf(fmaxf(vv, NZF), 1.0f - NZF);
                float et = fminf(pe[j] * sprop, vad);
                vad -= et;
                float spq    = fexp2(qn * flog2(sprop));
                float qf_top = fminf(qf_top_coef * spq, vad);
                float qf_vic = fminf(mmax * spq, vad);
                float qf = fminf(w7qk * vad + w8 * qf_top + w9 * qf_vic, vad);
                vad -= qf;
                float perc = cv2p * vad;
                vad -= perc;
                phr += perc;
                float pb = fexp2(bn * flog2(fmaxf(phr, NZF)));
                float bf = fminf(c_b1 * phr + c_b2 * pb, phr);
                phr -= bf;

                const size_t row = (size_t)(kg * GRP + j) * G_CELLS + (size_t)g;
                quick[row] = surface + qf;
                base[row]  = bf;
            }

            #pragma unroll
            for (int j = 0; j < GRP; ++j) pe[j] = rawPet[j] * ET_eff;
        }
    }
}

__global__ __launch_bounds__(256, 1) void pipeline_kernel(
    const float* __restrict__ x, const float* __restrict__ params,
    float* __restrict__ quick, float* __restrict__ base)
{
    __shared__ float ob[2][3][GRP][CPB];   // 12 KB ring: [buf][model][step-in-group][cell]
    const int lane = threadIdx.x & 63;
    const int wave = threadIdx.x >> 6;
    const int g    = blockIdx.x * CPB + lane;
    const float* pp = params + ((size_t)(T_STEPS - 1) * G_CELLS + (size_t)g) * 39;

    if (wave == 0)      snow_wave<0>(x, pp, ob, lane, g);
    else if (wave == 1) snow_wave<1>(x, pp, ob, lane, g);
    else if (wave == 2) snow_wave<2>(x, pp, ob, lane, g);
    else                vadose_wave(x, pp, ob, quick, base, lane, g);
}

// ===================== routing (proven R7-R9) =====================
__device__ __forceinline__ void make_uh(float a1, float b1, float a2, float b2,
                                        float* uh1, float* uh2) {
    const float LOG2T[L_UHN] = {
        -1.0f, 0.58496250072116f, 1.32192809488736f, 1.80735492205760f,
        2.16992500144231f, 2.45943161863730f, 2.70043971814109f,
        2.90689059560852f, 3.08746284125034f, 3.24792751344359f,
        3.39231742277876f, 3.52356195605701f, 3.64385618977472f,
        3.75488750216347f, 3.85798099512757f };
    float rb1 = LOG2E / b1, rb2 = LOG2E / b2;
    float s1 = 0.0f, s2 = 0.0f;
    #pragma unroll
    for (int k = 0; k < L_UHN; ++k) {
        float tk = (float)k + 0.5f;
        float v1 = fexp2((a1 - 1.0f) * LOG2T[k] - tk * rb1);
        float v2 = fexp2((a2 - 1.0f) * LOG2T[k] - tk * rb2);
        uh1[k] = v1; uh2[k] = v2; s1 += v1; s2 += v2;
    }
    float i1 = 1.0f / s1, i2 = 1.0f / s2;
    #pragma unroll
    for (int k = 0; k < L_UHN; ++k) { uh1[k] *= i1; uh2[k] *= i2; }
}

__global__ __launch_bounds__(64, 1) void route_tiled_kernel(
    const float* __restrict__ quick,
    const float* __restrict__ base,
    const float* __restrict__ params,
    float* __restrict__ out)
{
    const int g  = blockIdx.x * 64 + threadIdx.x;
    const int t0 = blockIdx.y * RT_T;

    const float* pp = params + ((size_t)(T_STEPS - 1) * G_CELLS + (size_t)g) * 39;
    float a1 = fdescale(fsigmoid(pp[35]), 0.3f, 20.0f);
    float b1 = fdescale(fsigmoid(pp[36]), 0.01f, 5.0f);
    float a2 = fdescale(fsigmoid(pp[37]), 0.5f, 13.0f);
    float b2 = fdescale(fsigmoid(pp[38]), 0.15f, 1.5f);
    float uh1[L_UHN], uh2[L_UHN];
    make_uh(a1, b1, a2, b2, uh1, uh2);

    float qw[RT_T + L_UHN - 1], bw[RT_T + L_UHN - 1];
    #pragma unroll
    for (int i = 0; i < RT_T + L_UHN - 1; ++i) {
        int t = t0 + i - (L_UHN - 1);
        bool ok = (t >= 0);
        size_t a = (size_t)(ok ? t : 0) * G_CELLS + (size_t)g;
        qw[i] = ok ? quick[a] : 0.0f;
        bw[i] = ok ? base[a]  : 0.0f;
    }

    #pragma unroll
    for (int j = 0; j < RT_T; ++j) {
        float acc = 0.0f;
        #pragma unroll
        for (int k = 0; k < L_UHN; ++k)
            acc = fmaf(uh1[k], qw[j + L_UHN - 1 - k], fmaf(uh2[k], bw[j + L_UHN - 1 - k], acc));
        out[(size_t)(t0 + j) * G_CELLS + (size_t)g] = acc;
    }
}

// ===================== fused fallback (proven R4 structure) =====================
__global__ __launch_bounds__(256) void fused_kernel(
    const float* __restrict__ x, const float* __restrict__ params, float* __restrict__ out)
{
    const int g = blockIdx.x * blockDim.x + threadIdx.x;
    const float* pp = params + ((size_t)(T_STEPS - 1) * G_CELLS + (size_t)g) * 39;

    const float ddf_min     = fdescale(fsigmoid(pp[0]),  0.0f, 20.0f);
    const float ddf_plus    = fdescale(fsigmoid(pp[1]),  0.0f, 20.0f);
    const float Kcum        = fdescale(fsigmoid(pp[2]),  0.01f, 0.2f);
    const float Kf          = fdescale(fsigmoid(pp[3]),  0.0f, 5.0f);
    const float exp_fe      = fdescale(fsigmoid(pp[4]),  0.0f, 1.0f);
    const float Tbf         = fdescale(fsigmoid(pp[5]), -5.0f, 2.0f);
    const float Ccum        = fdescale(fsigmoid(pp[6]),  0.005f, 0.05f);
    const float SWI         = fdescale(fsigmoid(pp[7]),  0.0f, 0.4f);
    const float Tbm         = fdescale(fsigmoid(pp[8]), -2.0f, 3.0f);
    const float fcmin       = fdescale(fsigmoid(pp[9]),  0.0f, 0.1f);
    const float fcmin_plus  = fdescale(fsigmoid(pp[10]), 0.01f, 0.25f);
    const float vmax        = fdescale(fsigmoid(pp[11]), 0.001f, 500.0f);
    const float hmets_alpha = fdescale(fsigmoid(pp[12]), 0.0f, 1.0f);
    const float vic_beta    = fdescale(fsigmoid(pp[13]), 0.1f, 3.0f);
    const float hbv_beta    = fdescale(fsigmoid(pp[14]), 0.5f, 3.0f);
    const float quickflow_k = fdescale(fsigmoid(pp[15]), -5.0f, -2.0f);
    const float qn          = fdescale(fsigmoid(pp[16]), 0.5f, 2.0f);
    const float mmax        = fdescale(fsigmoid(pp[17]), 0.0f, 100.0f);
    const float lamb        = fdescale(fsigmoid(pp[18]), 5.0f, 10.0f);
    const float baseflow_k  = fdescale(fsigmoid(pp[19]), -5.0f, -1.0f);
    const float bn          = fdescale(fsigmoid(pp[20]), 0.5f, 2.0f);
    const float ET_eff      = fdescale(fsigmoid(pp[21]), 0.0f, 3.0f);
    const float cv2p        = fdescale(fsigmoid(pp[22]), 1e-5f, 0.02f);

    float w1,w2,w3,w4,w5,w6,w7,w8,w9,w10,w11;
    {
        float m = fmaxf(fmaxf(pp[24], pp[25]), pp[26]);
        float e0 = fexp(pp[24]-m), e1 = fexp(pp[25]-m), e2 = fexp(pp[26]-m);
        float inv = 1.0f/(e0+e1+e2); w1=e0*inv; w2=e1*inv; w3=e2*inv;
    }
    {
        float m = fmaxf(fmaxf(pp[27], pp[28]), pp[29]);
        float e0 = fexp(pp[27]-m), e1 = fexp(pp[28]-m), e2 = fexp(pp[29]-m);
        float inv = 1.0f/(e0+e1+e2); w4=e0*inv; w5=e1*inv; w6=e2*inv;
    }
    {
        float m = fmaxf(fmaxf(pp[30], pp[31]), pp[32]);
        float e0 = fexp(pp[30]-m), e1 = fexp(pp[31]-m), e2 = fexp(pp[32]-m);
        float inv = 1.0f/(e0+e1+e2); w7=e0*inv; w8=e1*inv; w9=e2*inv;
    }
    {
        float m = fmaxf(pp[33], pp[34]);
        float e0 = fexp(pp[33]-m), e1 = fexp(pp[34]-m);
        float inv = 1.0f/(e0+e1); w10=e0*inv; w11=e1*inv;
    }

    float uh1[L_UHN], uh2[L_UHN];
    make_uh(fdescale(fsigmoid(pp[35]), 0.3f, 20.0f), fdescale(fsigmoid(pp[36]), 0.01f, 5.0f),
            fdescale(fsigmoid(pp[37]), 0.5f, 13.0f), fdescale(fsigmoid(pp[38]), 0.15f, 1.5f),
            uh1, uh2);

    const float ddfsum = ddf_min + ddf_plus;
    const float ddfK   = ddf_min * Kcum;
    const float inv_vmax = 1.0f / vmax;
    const float qk10 = fexp2(quickflow_k * LOG2_10);
    const float bk10 = fexp2(baseflow_k * LOG2_10);
    const float qf_top_coef = mmax * (vmax / qn) * fexp2(-qn * flog2(lamb));
    const float fcsum = fcmin + fcmin_plus;
    const float c_b1 = w10 * bk10, c_b2 = w11 * bk10, w7qk = w7 * qk10;

    float sp1=0,lw1=0,cm1=0, sp2=0,lw2=0,cm2=0, sp3=0,cm3=0, vad=0, phr=0;
    float fut[L_UHN];
    #pragma unroll
    for (int k = 0; k < L_UHN; ++k) fut[k] = 0.0f;

    for (int t = 0; t < T_STEPS; ++t) {
        size_t a = ((size_t)t * G_CELLS + (size_t)g) * 3;
        const float prcp = x[a], tm = x[a+1], pet = x[a+2];
        const float rain = (tm > 0.0f) ? prcp : 0.0f;
        const float snow = prcp - rain;
        const float frz = fmaxf(Tbf - tm, NZF);

        float o1;
        {
            float ddf = fminf(ddfsum, fmaf(ddfK, cm1, ddf_min));
            float pm  = fmaxf(ddf * (tm - Tbm), 0.0f);
            float rfz = fminf(Kf * frz, lw1);
            sp1 = sp1 + snow + rfz;
            float melt = fminf(pm, sp1 + snow + rfz);
            cm1 = (sp1 > NZF) ? (cm1 + melt) : 0.0f;
            sp1 = fmaxf(sp1 - melt, NZF);
            float wret = SWI * sp1, wtmp = lw1 + melt + rain;
            o1 = fmaxf(wtmp - wret, 0.0f);
            lw1 = fminf(wtmp, wret);
        }
        float o2;
        {
            float ddf = fminf(ddfsum, fmaf(ddfK, cm2, ddf_min));
            float pm  = fmaxf(ddf * (tm - Tbm), 0.0f);
            float pfz = Kf * fpow(frz, exp_fe);
            float rfz = fminf(pfz, lw2);
            lw2 -= rfz; sp2 += rfz;
            float melt = fminf(pm, sp2 + snow);
            sp2 = sp2 + snow - melt;
            cm2 = (sp2 > NZF) ? (cm2 + melt) : 0.0f;
            float wrf = fmaxf(fcsum * (1.0f - Ccum * cm2), fcmin);
            float wret = wrf * sp2, wtmp = lw2 + melt + rain;
            o2 = fmaxf(wtmp - wret, 0.0f);
            lw2 = fminf(wtmp, wret);
            cm2 = (sp2 > NZF) ? (cm2 + melt) : 0.0f;
        }
        float o3;
        {
            float ddf = fminf(ddfsum, fmaf(ddfK, cm3, ddf_min));
            float pm  = fmaxf(ddf * (tm - Tbm), 0.0f);
            float melt = fminf(pm, sp3);
            sp3 = sp3 + snow - melt;
            o3 = melt + rain;
            cm3 = (sp3 > NZF) ? (cm3 + melt) : 0.0f;
        }

        float rr = w1*o1 + w2*o2 + w3*o3;
        float vv = vad * inv_vmax;
        float sprop = fminf(fmaxf(vv, NZF), 1.0f - NZF);
        float l1 = flog2(1.0f - sprop);
        float phbv = fexp2(hbv_beta * l1);
        float pvic = fexp2(vic_beta * l1);
        float inf = w4*rr*phbv + w5*rr*(1.0f - hmets_alpha*vv) + w6*rr*(1.0f - pvic);
        inf = fminf(fmaxf(inf, 0.0f), rr);
        float surface = rr - inf;
        vad += inf;
        vv = vad * inv_vmax;
        sprop = fminf(fmaxf(vv, NZF), 1.0f - NZF);
        float et = fminf(pet * ET_eff * sprop, vad);
        vad -= et;
        float spq = fexp2(qn * flog2(sprop));
        float qf_top = fminf(qf_top_coef * spq, vad);
        float qf_vic = fminf(mmax * spq, vad);
        float qf = fminf(w7qk*vad + w8*qf_top + w9*qf_vic, vad);
        vad -= qf;
        float perc = cv2p * vad;
        vad -= perc;
        phr += perc;
        float pb = fexp2(bn * flog2(fmaxf(phr, NZF)));
        float bf = fminf(c_b1*phr + c_b2*pb, phr);
        phr -= bf;

        float qt = surface + qf;
        #pragma unroll
        for (int k = 0; k < L_UHN; ++k)
            fut[k] = fmaf(uh1[k], qt, fmaf(uh2[k], bf, fut[k]));
        out[(size_t)t * G_CELLS + (size_t)g] = fut[0];
        #pragma unroll
        for (int k = 0; k < L_UHN - 1; ++k) fut[k] = fut[k + 1];
        fut[L_UHN - 1] = 0.0f;
    }
}

extern "C" void kernel_launch(void* const* d_in, const int* in_sizes, int n_in,
                              void* d_out, int out_size, void* d_ws, size_t ws_size,
                              hipStream_t stream) {
    const float* x      = (const float*)d_in[0];
    const float* params = (const float*)d_in[1];
    float* out          = (float*)d_out;

    if (ws_size >= 2 * PLANE_BYTES) {
        float* quick = (float*)d_ws;
        float* base  = quick + PLANE;
        pipeline_kernel<<<dim3(G_CELLS / CPB), dim3(256), 0, stream>>>(x, params, quick, base);
        route_tiled_kernel<<<dim3(G_CELLS / 64, T_STEPS / RT_T), dim3(64), 0, stream>>>(
            quick, base, params, out);
    } else {
        fused_kernel<<<dim3(G_CELLS / 256), dim3(256), 0, stream>>>(x, params, out);
    }
}

// Round 11
// 75.615 us; speedup vs baseline: 2.2616x; 1.2746x over previous
//
#include <hip/hip_runtime.h>

#define T_STEPS 512
#define G_CELLS 4096
#define L_UHN   15
#define GRP     8
#define NGRP    (T_STEPS / GRP)   // 64
#define CPB     64                // cells per block (one lane each)
#define NZF     1e-5f
#define LOG2E   1.44269504088896340736f
#define LOG2_10 3.32192809488736234787f

__device__ __forceinline__ float fexp2(float x) { return __builtin_amdgcn_exp2f(x); }
__device__ __forceinline__ float flog2(float x) { return __builtin_amdgcn_logf(x); }
__device__ __forceinline__ float fpow(float a, float b) { return fexp2(b * flog2(a)); }
__device__ __forceinline__ float fexp(float x) { return fexp2(x * LOG2E); }
__device__ __forceinline__ float fsigmoid(float v) { return 1.0f / (1.0f + fexp(-v)); }
__device__ __forceinline__ float fdescale(float s, float lo, float hi) { return lo + s * (hi - lo); }

__device__ __forceinline__ void block_barrier() {
    asm volatile("s_waitcnt lgkmcnt(0)" ::: "memory");
    __builtin_amdgcn_s_barrier();
}

// ob ring: weighted snow outputs  [buf][model][step][cell]
// pr ring: vad-wave outputs       [buf][0=perc,1=quick][step][cell]

// ===================== wave 0: hbv + simple snow models =====================
__device__ __forceinline__ void snow02_wave(const float* __restrict__ x,
                                            const float* __restrict__ pp,
                                            float (*ob)[3][GRP][CPB],
                                            int lane, int g)
{
    const float ddf_min  = fdescale(fsigmoid(pp[0]), 0.0f, 20.0f);
    const float ddf_plus = fdescale(fsigmoid(pp[1]), 0.0f, 20.0f);
    const float Kcum     = fdescale(fsigmoid(pp[2]), 0.01f, 0.2f);
    const float Kf       = fdescale(fsigmoid(pp[3]), 0.0f, 5.0f);
    const float Tbf      = fdescale(fsigmoid(pp[5]), -5.0f, 2.0f);
    const float SWI      = fdescale(fsigmoid(pp[7]), 0.0f, 0.4f);
    const float Tbm      = fdescale(fsigmoid(pp[8]), -2.0f, 3.0f);
    const float ddfsum   = ddf_min + ddf_plus;
    const float ddfK     = ddf_min * Kcum;

    float w0, w2_;
    {
        float r0 = pp[24], r1 = pp[25], r2 = pp[26];
        float m = fmaxf(fmaxf(r0, r1), r2);
        float e0 = fexp(r0 - m), e1 = fexp(r1 - m), e2 = fexp(r2 - m);
        float inv = 1.0f / (e0 + e1 + e2);
        w0 = e0 * inv; w2_ = e2 * inv;
    }

    float sp0 = 0.f, lw0 = 0.f, cm0 = 0.f;   // hbv
    float sp2 = 0.f, cm2 = 0.f;              // simple

    float bR[GRP], bS[GRP], bD[GRP], bX[GRP];
    float rawP[GRP], rawT[GRP];
    #pragma unroll
    for (int j = 0; j < GRP; ++j) {
        size_t a = ((size_t)j * G_CELLS + (size_t)g) * 3;
        rawP[j] = x[a]; rawT[j] = x[a + 1];
    }
    #pragma unroll
    for (int j = 0; j < GRP; ++j) {
        float tm = rawT[j], prcp = rawP[j];
        bR[j] = (tm > 0.0f) ? prcp : 0.0f;
        bS[j] = prcp - bR[j];
        bD[j] = tm - Tbm;
        bX[j] = Kf * fmaxf(Tbf - tm, NZF);
    }

    for (int k = 0; k <= NGRP + 1; ++k) {
        block_barrier();
        if (k < NGRP) {
            const int kn = (k + 1 < NGRP) ? k + 1 : NGRP - 1;
            #pragma unroll
            for (int j = 0; j < GRP; ++j) {
                size_t a = ((size_t)(kn * GRP + j) * G_CELLS + (size_t)g) * 3;
                rawP[j] = x[a]; rawT[j] = x[a + 1];
            }

            const int b = k & 1;
            #pragma unroll
            for (int j = 0; j < GRP; ++j) {
                const float rain = bR[j], snow = bS[j], dtm = bD[j];
                // hbv
                {
                    float ddf  = fminf(ddfsum, fmaf(ddfK, cm0, ddf_min));
                    float pm   = fmaxf(ddf * dtm, 0.0f);
                    float rfz  = fminf(bX[j], lw0);
                    sp0 = sp0 + snow + rfz;
                    float melt = fminf(pm, sp0 + snow + rfz);   // reference quirk
                    cm0 = (sp0 > NZF) ? (cm0 + melt) : 0.0f;
                    sp0 = fmaxf(sp0 - melt, NZF);
                    float wret = SWI * sp0;
                    float wtmp = lw0 + melt + rain;
                    float o    = fmaxf(wtmp - wret, 0.0f);
                    lw0 = fminf(wtmp, wret);
                    ob[b][0][j][lane] = w0 * o;
                }
                // simple
                {
                    float ddf  = fminf(ddfsum, fmaf(ddfK, cm2, ddf_min));
                    float pm   = fmaxf(ddf * dtm, 0.0f);
                    float melt = fminf(pm, sp2);
                    sp2 = sp2 + snow - melt;
                    float o = melt + rain;
                    cm2 = (sp2 > NZF) ? (cm2 + melt) : 0.0f;
                    ob[b][2][j][lane] = w2_ * o;
                }
            }

            #pragma unroll
            for (int j = 0; j < GRP; ++j) {
                float tm = rawT[j], prcp = rawP[j];
                bR[j] = (tm > 0.0f) ? prcp : 0.0f;
                bS[j] = prcp - bR[j];
                bD[j] = tm - Tbm;
                bX[j] = Kf * fmaxf(Tbf - tm, NZF);
            }
        }
    }
}

// ===================== wave 1: hmets snow model =====================
__device__ __forceinline__ void snow1_wave(const float* __restrict__ x,
                                           const float* __restrict__ pp,
                                           float (*ob)[3][GRP][CPB],
                                           int lane, int g)
{
    const float ddf_min  = fdescale(fsigmoid(pp[0]), 0.0f, 20.0f);
    const float ddf_plus = fdescale(fsigmoid(pp[1]), 0.0f, 20.0f);
    const float Kcum     = fdescale(fsigmoid(pp[2]), 0.01f, 0.2f);
    const float Kf       = fdescale(fsigmoid(pp[3]), 0.0f, 5.0f);
    const float exp_fe   = fdescale(fsigmoid(pp[4]), 0.0f, 1.0f);
    const float Tbf      = fdescale(fsigmoid(pp[5]), -5.0f, 2.0f);
    const float Ccum     = fdescale(fsigmoid(pp[6]), 0.005f, 0.05f);
    const float Tbm      = fdescale(fsigmoid(pp[8]), -2.0f, 3.0f);
    const float fcmin    = fdescale(fsigmoid(pp[9]), 0.0f, 0.1f);
    const float fcsum    = fcmin + fdescale(fsigmoid(pp[10]), 0.01f, 0.25f);
    const float ddfsum   = ddf_min + ddf_plus;
    const float ddfK     = ddf_min * Kcum;

    float w1;
    {
        float r0 = pp[24], r1 = pp[25], r2 = pp[26];
        float m = fmaxf(fmaxf(r0, r1), r2);
        float e0 = fexp(r0 - m), e1 = fexp(r1 - m), e2 = fexp(r2 - m);
        w1 = e1 / (e0 + e1 + e2);
    }

    float sp = 0.f, lw = 0.f, cm = 0.f;

    float bR[GRP], bS[GRP], bD[GRP], bX[GRP];
    float rawP[GRP], rawT[GRP];
    #pragma unroll
    for (int j = 0; j < GRP; ++j) {
        size_t a = ((size_t)j * G_CELLS + (size_t)g) * 3;
        rawP[j] = x[a]; rawT[j] = x[a + 1];
    }
    #pragma unroll
    for (int j = 0; j < GRP; ++j) {
        float tm = rawT[j], prcp = rawP[j];
        bR[j] = (tm > 0.0f) ? prcp : 0.0f;
        bS[j] = prcp - bR[j];
        bD[j] = tm - Tbm;
        bX[j] = Kf * fpow(fmaxf(Tbf - tm, NZF), exp_fe);
    }

    for (int k = 0; k <= NGRP + 1; ++k) {
        block_barrier();
        if (k < NGRP) {
            const int kn = (k + 1 < NGRP) ? k + 1 : NGRP - 1;
            #pragma unroll
            for (int j = 0; j < GRP; ++j) {
                size_t a = ((size_t)(kn * GRP + j) * G_CELLS + (size_t)g) * 3;
                rawP[j] = x[a]; rawT[j] = x[a + 1];
            }

            const int b = k & 1;
            #pragma unroll
            for (int j = 0; j < GRP; ++j) {
                const float rain = bR[j], snow = bS[j], dtm = bD[j];
                float ddf  = fminf(ddfsum, fmaf(ddfK, cm, ddf_min));
                float pm   = fmaxf(ddf * dtm, 0.0f);
                float rfz  = fminf(bX[j], lw);
                lw -= rfz; sp += rfz;
                float melt = fminf(pm, sp + snow);
                sp = sp + snow - melt;
                cm = (sp > NZF) ? (cm + melt) : 0.0f;
                float wrf  = fmaxf(fcsum * (1.0f - Ccum * cm), fcmin);
                float wret = wrf * sp;
                float wtmp = lw + melt + rain;
                float o    = fmaxf(wtmp - wret, 0.0f);
                lw = fminf(wtmp, wret);
                cm = (sp > NZF) ? (cm + melt) : 0.0f;      // reference quirk: double update
                ob[b][1][j][lane] = w1 * o;
            }

            #pragma unroll
            for (int j = 0; j < GRP; ++j) {
                float tm = rawT[j], prcp = rawP[j];
                bR[j] = (tm > 0.0f) ? prcp : 0.0f;
                bS[j] = prcp - bR[j];
                bD[j] = tm - Tbm;
                bX[j] = Kf * fpow(fmaxf(Tbf - tm, NZF), exp_fe);
            }
        }
    }
}

// ===================== wave 2: vadose chain =====================
__device__ __forceinline__ void vad_wave(const float* __restrict__ x,
                                         const float* __restrict__ pp,
                                         float (*ob)[3][GRP][CPB],
                                         float (*pr)[2][GRP][CPB],
                                         int lane, int g)
{
    const float vmax        = fdescale(fsigmoid(pp[11]), 0.001f, 500.0f);
    const float hmets_alpha = fdescale(fsigmoid(pp[12]), 0.0f, 1.0f);
    const float vic_beta    = fdescale(fsigmoid(pp[13]), 0.1f, 3.0f);
    const float hbv_beta    = fdescale(fsigmoid(pp[14]), 0.5f, 3.0f);
    const float quickflow_k = fdescale(fsigmoid(pp[15]), -5.0f, -2.0f);
    const float qn          = fdescale(fsigmoid(pp[16]), 0.5f, 2.0f);
    const float mmax        = fdescale(fsigmoid(pp[17]), 0.0f, 100.0f);
    const float lamb        = fdescale(fsigmoid(pp[18]), 5.0f, 10.0f);
    const float ET_eff      = fdescale(fsigmoid(pp[21]), 0.0f, 3.0f);
    const float cv2p        = fdescale(fsigmoid(pp[22]), 1e-5f, 0.02f);

    float w4, w5, w6, w7, w8, w9;
    {
        float r0 = pp[27], r1 = pp[28], r2 = pp[29];
        float m = fmaxf(fmaxf(r0, r1), r2);
        float e0 = fexp(r0 - m), e1 = fexp(r1 - m), e2 = fexp(r2 - m);
        float inv = 1.0f / (e0 + e1 + e2);
        w4 = e0 * inv; w5 = e1 * inv; w6 = e2 * inv;
    }
    {
        float r0 = pp[30], r1 = pp[31], r2 = pp[32];
        float m = fmaxf(fmaxf(r0, r1), r2);
        float e0 = fexp(r0 - m), e1 = fexp(r1 - m), e2 = fexp(r2 - m);
        float inv = 1.0f / (e0 + e1 + e2);
        w7 = e0 * inv; w8 = e1 * inv; w9 = e2 * inv;
    }

    const float inv_vmax    = 1.0f / vmax;
    const float qk10        = fexp2(quickflow_k * LOG2_10);
    const float qf_top_coef = mmax * (vmax / qn) * fexp2(-qn * flog2(lamb));
    const float w7qk        = w7 * qk10;

    float vad = 0.f;

    float pe[GRP], rawPet[GRP];
    #pragma unroll
    for (int j = 0; j < GRP; ++j)
        rawPet[j] = x[((size_t)j * G_CELLS + (size_t)g) * 3 + 2];
    #pragma unroll
    for (int j = 0; j < GRP; ++j) pe[j] = rawPet[j] * ET_eff;

    for (int k = 0; k <= NGRP + 1; ++k) {
        block_barrier();
        if (k >= 1 && k <= NGRP) {
            const int kg = k - 1;
            const int kn = (k < NGRP) ? k : NGRP - 1;
            #pragma unroll
            for (int j = 0; j < GRP; ++j)
                rawPet[j] = x[((size_t)(kn * GRP + j) * G_CELLS + (size_t)g) * 3 + 2];

            const int b = kg & 1;
            float rr[GRP];
            #pragma unroll
            for (int j = 0; j < GRP; ++j)
                rr[j] = (ob[b][0][j][lane] + ob[b][1][j][lane]) + ob[b][2][j][lane];

            #pragma unroll
            for (int j = 0; j < GRP; ++j) {
                const float rrj = rr[j];
                float vv = vad * inv_vmax;
                float sprop = fminf(fmaxf(vv, NZF), 1.0f - NZF);
                float l1 = flog2(1.0f - sprop);
                float phbv = fexp2(hbv_beta * l1);
                float pvic = fexp2(vic_beta * l1);
                float inf = w4 * rrj * phbv + w5 * rrj * (1.0f - hmets_alpha * vv)
                          + w6 * rrj * (1.0f - pvic);
                inf = fminf(fmaxf(inf, 0.0f), rrj);
                float surface = rrj - inf;
                vad += inf;
                vv = vad * inv_vmax;
                sprop = fminf(fmaxf(vv, NZF), 1.0f - NZF);
                float et = fminf(pe[j] * sprop, vad);
                vad -= et;
                float spq    = fexp2(qn * flog2(sprop));
                float qf_top = fminf(qf_top_coef * spq, vad);
                float qf_vic = fminf(mmax * spq, vad);
                float qf = fminf(w7qk * vad + w8 * qf_top + w9 * qf_vic, vad);
                vad -= qf;
                float perc = cv2p * vad;
                vad -= perc;

                pr[b][0][j][lane] = perc;
                pr[b][1][j][lane] = surface + qf;
            }

            #pragma unroll
            for (int j = 0; j < GRP; ++j) pe[j] = rawPet[j] * ET_eff;
        }
    }
}

// ===================== wave 3: phreatic chain + fused routing =====================
__device__ __forceinline__ void phr_route_wave(const float* __restrict__ pp,
                                               float (*pr)[2][GRP][CPB],
                                               float* __restrict__ out,
                                               int lane, int g)
{
    const float baseflow_k = fdescale(fsigmoid(pp[19]), -5.0f, -1.0f);
    const float bn         = fdescale(fsigmoid(pp[20]), 0.5f, 2.0f);
    float w10, w11;
    {
        float r0 = pp[33], r1 = pp[34];
        float m = fmaxf(r0, r1);
        float e0 = fexp(r0 - m), e1 = fexp(r1 - m);
        float inv = 1.0f / (e0 + e1);
        w10 = e0 * inv; w11 = e1 * inv;
    }
    const float bk10 = fexp2(baseflow_k * LOG2_10);
    const float c_b1 = w10 * bk10, c_b2 = w11 * bk10;

    const float a1 = fdescale(fsigmoid(pp[35]), 0.3f, 20.0f);
    const float b1 = fdescale(fsigmoid(pp[36]), 0.01f, 5.0f);
    const float a2 = fdescale(fsigmoid(pp[37]), 0.5f, 13.0f);
    const float b2 = fdescale(fsigmoid(pp[38]), 0.15f, 1.5f);

    const float LOG2T[L_UHN] = {
        -1.0f, 0.58496250072116f, 1.32192809488736f, 1.80735492205760f,
        2.16992500144231f, 2.45943161863730f, 2.70043971814109f,
        2.90689059560852f, 3.08746284125034f, 3.24792751344359f,
        3.39231742277876f, 3.52356195605701f, 3.64385618977472f,
        3.75488750216347f, 3.85798099512757f };

    float uh1[L_UHN], uh2[L_UHN];
    {
        float rb1 = LOG2E / b1, rb2 = LOG2E / b2;
        float s1 = 0.0f, s2 = 0.0f;
        #pragma unroll
        for (int kk = 0; kk < L_UHN; ++kk) {
            float tk = (float)kk + 0.5f;
            float v1 = fexp2((a1 - 1.0f) * LOG2T[kk] - tk * rb1);
            float v2 = fexp2((a2 - 1.0f) * LOG2T[kk] - tk * rb2);
            uh1[kk] = v1; uh2[kk] = v2; s1 += v1; s2 += v2;
        }
        float i1 = 1.0f / s1, i2 = 1.0f / s2;
        #pragma unroll
        for (int kk = 0; kk < L_UHN; ++kk) { uh1[kk] *= i1; uh2[kk] *= i2; }
    }

    float phr = 0.f;
    float fut[L_UHN];
    #pragma unroll
    for (int kk = 0; kk < L_UHN; ++kk) fut[kk] = 0.0f;

    for (int k = 0; k <= NGRP + 1; ++k) {
        block_barrier();
        if (k >= 2) {
            const int kp = k - 2;
            const int b  = kp & 1;
            float pc[GRP], qv[GRP];
            #pragma unroll
            for (int j = 0; j < GRP; ++j) {
                pc[j] = pr[b][0][j][lane];
                qv[j] = pr[b][1][j][lane];
            }

            #pragma unroll
            for (int j = 0; j < GRP; ++j) {
                phr += pc[j];
                float pb = fexp2(bn * flog2(fmaxf(phr, NZF)));
                float bf = fminf(c_b1 * phr + c_b2 * pb, phr);
                phr -= bf;

                const float qt = qv[j];
                #pragma unroll
                for (int kk = 0; kk < L_UHN; ++kk)
                    fut[kk] = fmaf(uh1[kk], qt, fmaf(uh2[kk], bf, fut[kk]));
                out[(size_t)(kp * GRP + j) * G_CELLS + (size_t)g] = fut[0];
                #pragma unroll
                for (int kk = 0; kk < L_UHN - 1; ++kk) fut[kk] = fut[kk + 1];
                fut[L_UHN - 1] = 0.0f;
            }
        }
    }
}

__global__ __launch_bounds__(256, 1) void pipeline_kernel(
    const float* __restrict__ x, const float* __restrict__ params,
    float* __restrict__ out)
{
    __shared__ float ob[2][3][GRP][CPB];   // 12 KB
    __shared__ float pr[2][2][GRP][CPB];   //  8 KB
    const int lane = threadIdx.x & 63;
    const int wave = threadIdx.x >> 6;
    const int g    = blockIdx.x * CPB + lane;
    const float* pp = params + ((size_t)(T_STEPS - 1) * G_CELLS + (size_t)g) * 39;

    if (wave == 0)      snow02_wave(x, pp, ob, lane, g);
    else if (wave == 1) snow1_wave(x, pp, ob, lane, g);
    else if (wave == 2) vad_wave(x, pp, ob, pr, lane, g);
    else                phr_route_wave(pp, pr, out, lane, g);
}

extern "C" void kernel_launch(void* const* d_in, const int* in_sizes, int n_in,
                              void* d_out, int out_size, void* d_ws, size_t ws_size,
                              hipStream_t stream) {
    const float* x      = (const float*)d_in[0];
    const float* params = (const float*)d_in[1];
    float* out          = (float*)d_out;
    pipeline_kernel<<<dim3(G_CELLS / CPB), dim3(256), 0, stream>>>(x, params, out);
}